// Round 1
// baseline (66.496 us; speedup 1.0000x reference)
//
#include <hip/hip_runtime.h>
#include <hip/hip_bf16.h>

// out[n,f] = weights[n] * ( x[n,:] . Wsum[f,:] + bsum[f] )
// Wsum = sum_e W[e], bsum = sum_e b[e]   (expert sum commutes with Linear)

#define N_TOK 32768
#define DIM   512
#define NEXP  8

typedef __attribute__((ext_vector_type(8))) short  bf16x8;
typedef __attribute__((ext_vector_type(4))) float  f32x4;

__device__ __forceinline__ unsigned int pk2bf(float a, float b) {
    unsigned ua = __float_as_uint(a), ub = __float_as_uint(b);
    ua = (ua + 0x7FFFu + ((ua >> 16) & 1u)) >> 16;   // RNE to bf16
    ub = (ub + 0x7FFFu + ((ub >> 16) & 1u)) >> 16;
    return ua | (ub << 16);
}

// ---------------- prep: Wsum (bf16) + bsum (f32) ----------------
__global__ __launch_bounds__(256) void moe_prep(const float* __restrict__ W,
                                                const float* __restrict__ b,
                                                unsigned short* __restrict__ Wsum,
                                                float* __restrict__ bsum) {
    int g  = blockIdx.x * 256 + threadIdx.x;     // 0 .. 65535
    int e4 = g * 4;                              // 4 consecutive elements of [D*D]
    float4 s = make_float4(0.f, 0.f, 0.f, 0.f);
#pragma unroll
    for (int e = 0; e < NEXP; ++e) {
        float4 v = *(const float4*)(W + e * (DIM * DIM) + e4);
        s.x += v.x; s.y += v.y; s.z += v.z; s.w += v.w;
    }
    uint2 o;
    o.x = pk2bf(s.x, s.y);
    o.y = pk2bf(s.z, s.w);
    *(uint2*)(Wsum + e4) = o;

    if (g < DIM / 4) {
        float4 bs = make_float4(0.f, 0.f, 0.f, 0.f);
#pragma unroll
        for (int e = 0; e < NEXP; ++e) {
            float4 v = *(const float4*)(b + e * DIM + g * 4);
            bs.x += v.x; bs.y += v.y; bs.z += v.z; bs.w += v.w;
        }
        *(float4*)(bsum + g * 4) = bs;
    }
}

// ---------------- main GEMM ----------------
// Tile: BM=128 (tokens) x BF=128 (out-features), BK=64.
// 256 threads = 4 waves in 2x2, each wave 64x64 via 4x4 frags of 16x16x32 bf16 MFMA.
#define BM 128
#define BF 128
#define BK 64

__global__ __launch_bounds__(256) void moe_gemm(const float* __restrict__ x,
                                                const float* __restrict__ wts,
                                                const unsigned short* __restrict__ Ws,
                                                const float* __restrict__ bsum,
                                                float* __restrict__ out) {
    __shared__ unsigned short ldsA[BM * BK];   // 16 KB, XOR-swizzled
    __shared__ unsigned short ldsB[BF * BK];   // 16 KB, XOR-swizzled

    const int tid  = threadIdx.x;
    const int lane = tid & 63;
    const int wid  = tid >> 6;            // 0..3
    const int wm0  = (wid >> 1) * 64;     // wave row offset in tile
    const int wf0  = (wid & 1) * 64;      // wave col offset in tile

    // XCD-aware mapping: 1024 blocks, XCD = blockIdx % 8 (round-robin heuristic).
    // Give each XCD a contiguous band of 32 M-tiles; its 4 F-tiles per M-tile are
    // temporally adjacent -> A panel (256 KB) is L2-resident for all 4 re-reads.
    const int d    = blockIdx.x;
    const int xcd  = d & 7;
    const int li   = d >> 3;              // 0..127
    const int bm_t = xcd * 32 + (li >> 2);
    const int bf_t = li & 3;
    const int bm0  = bm_t * BM;
    const int bf0  = bf_t * BF;

    f32x4 acc[4][4] = {};

    uint4 pa[4], pb[4];

    auto LOAD = [&](int ks) {
        const int k0 = ks * BK;
#pragma unroll
        for (int it = 0; it < 4; ++it) {
            int c   = it * 256 + tid;     // chunk 0..1023
            int row = c >> 3;             // 0..127
            int k8  = (c & 7) * 8;        // 0,8,..,56
            const float4* p = (const float4*)(x + (size_t)(bm0 + row) * DIM + k0 + k8);
            float4 u0 = p[0], u1 = p[1];
            pa[it].x = pk2bf(u0.x, u0.y);
            pa[it].y = pk2bf(u0.z, u0.w);
            pa[it].z = pk2bf(u1.x, u1.y);
            pa[it].w = pk2bf(u1.z, u1.w);
            pb[it]   = *(const uint4*)(Ws + (size_t)(bf0 + row) * DIM + k0 + k8);
        }
    };
    auto STORE = [&]() {
#pragma unroll
        for (int it = 0; it < 4; ++it) {
            int c   = it * 256 + tid;
            int row = c >> 3;
            int k8  = (c & 7) * 8;
            int off = (row * BK + k8) ^ ((row & 7) << 3);   // 16B-granular XOR swizzle
            *(uint4*)(ldsA + off) = pa[it];
            *(uint4*)(ldsB + off) = pb[it];
        }
    };

    LOAD(0);
#pragma unroll 1
    for (int ks = 0; ks < DIM / BK; ++ks) {
        STORE();
        __syncthreads();
        if (ks < DIM / BK - 1) LOAD(ks + 1);   // prefetch next tile into regs (T14)

        const int lr = lane & 15;
        const int lg = lane >> 4;
#pragma unroll
        for (int kk = 0; kk < BK; kk += 32) {
            bf16x8 af[4], bfr[4];
            const int lk = kk + lg * 8;
#pragma unroll
            for (int i = 0; i < 4; ++i) {
                int rowA = wm0 + i * 16 + lr;
                int offA = (rowA * BK + lk) ^ ((rowA & 7) << 3);
                af[i] = *(const bf16x8*)(ldsA + offA);
                int rowB = wf0 + i * 16 + lr;
                int offB = (rowB * BK + lk) ^ ((rowB & 7) << 3);
                bfr[i] = *(const bf16x8*)(ldsB + offB);
            }
#pragma unroll
            for (int i = 0; i < 4; ++i)
#pragma unroll
                for (int j = 0; j < 4; ++j)
                    acc[i][j] = __builtin_amdgcn_mfma_f32_16x16x32_bf16(af[i], bfr[j], acc[i][j], 0, 0, 0);
        }
        __syncthreads();
    }

    // Epilogue: out[row,col] = w[row] * (acc + bsum[col])
    const int lr = lane & 15;
    const int lg = lane >> 4;
#pragma unroll
    for (int i = 0; i < 4; ++i) {
        int rbase = bm0 + wm0 + i * 16 + lg * 4;
        float w0 = wts[rbase + 0];
        float w1 = wts[rbase + 1];
        float w2 = wts[rbase + 2];
        float w3 = wts[rbase + 3];
#pragma unroll
        for (int j = 0; j < 4; ++j) {
            int col  = bf0 + wf0 + j * 16 + lr;
            float bs = bsum[col];
            float* o = out + (size_t)rbase * DIM + col;
            o[0 * DIM] = w0 * (acc[i][j][0] + bs);
            o[1 * DIM] = w1 * (acc[i][j][1] + bs);
            o[2 * DIM] = w2 * (acc[i][j][2] + bs);
            o[3 * DIM] = w3 * (acc[i][j][3] + bs);
        }
    }
}

extern "C" void kernel_launch(void* const* d_in, const int* in_sizes, int n_in,
                              void* d_out, int out_size, void* d_ws, size_t ws_size,
                              hipStream_t stream) {
    const float* x   = (const float*)d_in[0];   // [N, D]
    const float* wts = (const float*)d_in[1];   // [N, 1]
    const float* W   = (const float*)d_in[2];   // [E, D, D]
    const float* b   = (const float*)d_in[3];   // [E, D]
    float* out       = (float*)d_out;           // [N, D]

    unsigned short* Wsum = (unsigned short*)d_ws;                    // 512 KB bf16
    float*          bsum = (float*)((char*)d_ws + DIM * DIM * 2);    // 2 KB f32

    moe_prep<<<dim3((DIM * DIM / 4) / 256), dim3(256), 0, stream>>>(W, b, Wsum, bsum);

    moe_gemm<<<dim3((N_TOK / BM) * (DIM / BF)), dim3(256), 0, stream>>>(x, wts, Wsum, bsum, out);
}

// Round 3
// 57.110 us; speedup vs baseline: 1.1644x; 1.1644x over previous
//
#include <hip/hip_runtime.h>
#include <hip/hip_bf16.h>

// out[n,f] = weights[n] * ( x[n,:] . Wsum[f,:] + bsum[f] )
// Wsum = sum_e W[e] (bf16), bsum = sum_e b[e]  (expert sum commutes with Linear)

#define N_TOK 32768
#define DIM   512
#define NEXP  8
#define BM    64            // token rows per block
#define BK    64            // K per pipeline step
#define NKS   (DIM / BK)    // 8

typedef __attribute__((ext_vector_type(8))) short  bf16x8;
typedef __attribute__((ext_vector_type(4))) float  f32x4;

__device__ __forceinline__ unsigned int pk2bf(float a, float b) {
    unsigned ua = __float_as_uint(a), ub = __float_as_uint(b);
    ua = (ua + 0x7FFFu + ((ua >> 16) & 1u)) >> 16;   // RNE to bf16
    ub = (ub + 0x7FFFu + ((ub >> 16) & 1u)) >> 16;
    return ua | (ub << 16);
}

// ---------------- prep: Wsum (bf16, linear [DIM][DIM]) + bsum (f32) ----------------
__global__ __launch_bounds__(256) void moe_prep(const float* __restrict__ W,
                                                const float* __restrict__ b,
                                                unsigned short* __restrict__ Wsum,
                                                float* __restrict__ bsum) {
    int g  = blockIdx.x * 256 + threadIdx.x;     // 0 .. 65535
    int e4 = g * 4;
    float4 s = make_float4(0.f, 0.f, 0.f, 0.f);
#pragma unroll
    for (int e = 0; e < NEXP; ++e) {
        float4 v = *(const float4*)(W + e * (DIM * DIM) + e4);
        s.x += v.x; s.y += v.y; s.z += v.z; s.w += v.w;
    }
    uint2 o;
    o.x = pk2bf(s.x, s.y);
    o.y = pk2bf(s.z, s.w);
    *(uint2*)(Wsum + e4) = o;

    if (g < DIM / 4) {
        float4 bs = make_float4(0.f, 0.f, 0.f, 0.f);
#pragma unroll
        for (int e = 0; e < NEXP; ++e) {
            float4 v = *(const float4*)(b + e * DIM + g * 4);
            bs.x += v.x; bs.y += v.y; bs.z += v.z; bs.w += v.w;
        }
        *(float4*)(bsum + g * 4) = bs;
    }
}

// ---------------- main GEMM: block = [BM=64 tokens] x [all 512 features] ----------------
// 8 waves; wave w owns feature slice [w*64, (w+1)*64).
// A (x, f32->bf16) staged in LDS, double-buffered, XOR-swizzled (R0-proven, 0 conflicts).
// B (Wsum) read directly from global per-lane into MFMA operands (L2-resident), reg dbuf.
// MFMA operands swapped: D-row = feature, D-col = token -> lane owns 4 consecutive
// output features of one token -> direct dwordx4 stores, full-line write coverage.
__global__ __launch_bounds__(512, 2) void moe_gemm(const float* __restrict__ x,
                                                   const float* __restrict__ wts,
                                                   const unsigned short* __restrict__ Ws,
                                                   const float* __restrict__ bsum,
                                                   float* __restrict__ out) {
    __shared__ __align__(16) unsigned char ldsA[2][BM * BK * 2];   // 2 x 8 KB

    const int tid  = threadIdx.x;
    const int lane = tid & 63;
    const int w    = tid >> 6;       // wave 0..7
    const int lr   = lane & 15;
    const int lg   = lane >> 4;
    const int bm0  = blockIdx.x * BM;

    // ---- A staging: thread -> row tid>>3 (0..63), k-slot tid&7 (8 f32, coalesced)
    const int arow  = tid >> 3;
    const int aslot = tid & 7;
    const float* aptr = x + (size_t)(bm0 + arow) * DIM + aslot * 8;
    const int aoff  = arow * 128 + (((aslot) ^ (arow & 7)) << 4);   // swizzled bytes

    // ---- B fragment base: lane (lr,lg) of wave w reads feature row w*64 + j*16 + lr,
    //      k element (l>>4)*8 within each 32-k MFMA slice (standard fragment layout).
    const unsigned short* b0 = Ws + (size_t)(w * 64 + lr) * DIM + lg * 8;
    // fragment (j, kk) at step ks: b0 + j*16*DIM + ks*BK + kk*32

    f32x4 acc[4][4] = {};   // acc[j][i]: j = feature frag, i = token frag
    bf16x8 bE[4][2], bO[4][2];

    auto loadA = [&](int ks, float4& u0, float4& u1) {
        const float4* p = (const float4*)(aptr + ks * BK);
        u0 = p[0]; u1 = p[1];
    };
    auto storeA = [&](int buf, const float4& u0, const float4& u1) {
        uint4 v;
        v.x = pk2bf(u0.x, u0.y); v.y = pk2bf(u0.z, u0.w);
        v.z = pk2bf(u1.x, u1.y); v.w = pk2bf(u1.z, u1.w);
        *(uint4*)(&ldsA[buf][aoff]) = v;
    };
    auto compute = [&](int buf, bf16x8 (&bb)[4][2]) {
#pragma unroll
        for (int kk = 0; kk < 2; ++kk) {
            const int sw = (((kk * 4 + lg) ^ (lr & 7)) << 4);
            bf16x8 af[4];
#pragma unroll
            for (int i = 0; i < 4; ++i)
                af[i] = *(const bf16x8*)(&ldsA[buf][(i * 16 + lr) * 128 + sw]);
#pragma unroll
            for (int j = 0; j < 4; ++j)
#pragma unroll
                for (int i = 0; i < 4; ++i)
                    acc[j][i] = __builtin_amdgcn_mfma_f32_16x16x32_bf16(bb[j][kk], af[i], acc[j][i], 0, 0, 0);
        }
    };

    // ---- prologue: stage tile 0, prefetch B(0)
    {
        float4 u0, u1;
        loadA(0, u0, u1);
        storeA(0, u0, u1);
#pragma unroll
        for (int j = 0; j < 4; ++j) {
            bE[j][0] = *(const bf16x8*)(b0 + j * 16 * DIM);
            bE[j][1] = *(const bf16x8*)(b0 + j * 16 * DIM + 32);
        }
        __syncthreads();
    }

#pragma unroll
    for (int it = 0; it < 4; ++it) {
        const int ks1 = 2 * it + 1;
        // ---- even step: compute(buf0, bE); prefetch A(ks1)->buf1, B(ks1)->bO
        {
            float4 u0, u1;
            loadA(ks1, u0, u1);
#pragma unroll
            for (int j = 0; j < 4; ++j) {
                bO[j][0] = *(const bf16x8*)(b0 + j * 16 * DIM + ks1 * BK);
                bO[j][1] = *(const bf16x8*)(b0 + j * 16 * DIM + ks1 * BK + 32);
            }
            compute(0, bE);
            storeA(1, u0, u1);
            __syncthreads();
        }
        // ---- odd step: compute(buf1, bO); prefetch A(ks1+1)->buf0, B(ks1+1)->bE
        {
            float4 u0, u1;
            if (it < 3) {
                loadA(ks1 + 1, u0, u1);
#pragma unroll
                for (int j = 0; j < 4; ++j) {
                    bE[j][0] = *(const bf16x8*)(b0 + j * 16 * DIM + (ks1 + 1) * BK);
                    bE[j][1] = *(const bf16x8*)(b0 + j * 16 * DIM + (ks1 + 1) * BK + 32);
                }
            }
            compute(1, bO);
            if (it < 3) storeA(0, u0, u1);
            __syncthreads();
        }
    }

    // ---- epilogue: direct stores. Lane (lr,lg), frag (j,i):
    //      token = bm0 + i*16 + lr;  features = w*64 + j*16 + lg*4 + [0..3]
    f32x4 bs4[4];
#pragma unroll
    for (int j = 0; j < 4; ++j)
        bs4[j] = *(const f32x4*)(bsum + w * 64 + j * 16 + lg * 4);

#pragma unroll
    for (int i = 0; i < 4; ++i) {
        const int row = bm0 + i * 16 + lr;
        const float wt = wts[row];
#pragma unroll
        for (int j = 0; j < 4; ++j) {
            f32x4 v;
            v[0] = wt * (acc[j][i][0] + bs4[j][0]);
            v[1] = wt * (acc[j][i][1] + bs4[j][1]);
            v[2] = wt * (acc[j][i][2] + bs4[j][2]);
            v[3] = wt * (acc[j][i][3] + bs4[j][3]);
            *(f32x4*)(out + (size_t)row * DIM + w * 64 + j * 16 + lg * 4) = v;
        }
    }
}

extern "C" void kernel_launch(void* const* d_in, const int* in_sizes, int n_in,
                              void* d_out, int out_size, void* d_ws, size_t ws_size,
                              hipStream_t stream) {
    const float* x   = (const float*)d_in[0];   // [N, D]
    const float* wts = (const float*)d_in[1];   // [N, 1]
    const float* W   = (const float*)d_in[2];   // [E, D, D]
    const float* b   = (const float*)d_in[3];   // [E, D]
    float* out       = (float*)d_out;           // [N, D]

    unsigned short* Wsum = (unsigned short*)d_ws;                    // 512 KB bf16
    float*          bsum = (float*)((char*)d_ws + DIM * DIM * 2);    // 2 KB f32

    moe_prep<<<dim3((DIM * DIM / 4) / 256), dim3(256), 0, stream>>>(W, b, Wsum, bsum);

    moe_gemm<<<dim3(N_TOK / BM), dim3(512), 0, stream>>>(x, wts, Wsum, bsum, out);
}